// Round 10
// baseline (60.546 us; speedup 1.0000x reference)
//
#include <hip/hip_runtime.h>
#include <math.h>

namespace {

constexpr int T_ = 1024;
constexpr int HKV_ = 8;
constexpr int M_ = 8;
constexpr int D_ = 64;
constexpr int WIN_ = 128;
constexpr float SCALE_ = 0.125f;   // 1/sqrt(64)

constexpr int IB_ = 8;             // query rows per block (1 per wave)
constexpr int NKEY_ = 136;         // staged keys: [i0-127, i0+8]
constexpr int NTHREADS_ = 512;

using f4 = __attribute__((ext_vector_type(4))) float;

// float -> bf16 (round-nearest-even), packed pair
__device__ inline unsigned bf16rne_pack(float x, float y) {
    unsigned bx = __float_as_uint(x);
    unsigned by = __float_as_uint(y);
    bx = (bx + 0x7FFFu + ((bx >> 16) & 1u)) >> 16;
    by = (by + 0x7FFFu + ((by >> 16) & 1u)) >> 16;
    return bx | (by << 16);
}

// Round-9 structure (55.5us, clean) with exactly ONE change: K staged in LDS
// as packed bf16 (17.4 KB instead of 34.8 KB). Total LDS 34.1 KB -> 4
// blocks/CU if VGPR stays <=64 (round 9: exactly 64). More resident blocks
// = more phase diversity so the store pipe stays fed during other blocks'
// staging+fma bubbles. NO global loads post-barrier (R8: vmcnt is shared
// loads/stores, +16us). No launch_bounds (R6: VGPR cap => ~1GB spill tax).
__global__ void attn_qk_softmax(const float* __restrict__ qg,
                                const float* __restrict__ kg,
                                const float* __restrict__ sinks,
                                float* __restrict__ outg)
{
    // bf16 pairs; key row = 32 unsigned = 128B. Chunk c (4 vals, 8B) stored at
    // unsigned-index (2c) ^ (((r>>1)&15)<<1): 16 rotations x 8B cover all 32
    // banks; read conflicts <=4-way, write conflicts <=4-way (both cheap).
    __shared__ unsigned k_lds[NKEY_ * 32];       // 17.4 KB
    __shared__ unsigned q_lds[IB_][M_ * D_ / 2]; // bf16-packed q rows (8 KB)
    __shared__ float    p_lds[IB_][2][136];      // pad-17 probs, dbuf (8.7 KB)

    const int tid  = threadIdx.x;
    const int wave = tid >> 6;
    const int lane = tid & 63;
    const int h    = blockIdx.x / (T_ / IB_);
    const int i0   = (blockIdx.x % (T_ / IB_)) * IB_;
    const int base = i0 - (WIN_ - 1);            // global j of staged key r=0

    // ---- stage K window into LDS as bf16 (read f32x4, pack, 8B write) ----
    for (int f = tid; f < NKEY_ * 16; f += NTHREADS_) {
        const int r = f >> 4;
        const int c = f & 15;                    // 4-float chunk within row
        const int j = base + r;
        f4 v = {0.f, 0.f, 0.f, 0.f};
        if ((unsigned)j < (unsigned)T_)
            v = *reinterpret_cast<const f4*>(kg + ((size_t)j * HKV_ + h) * D_ + c * 4);
        uint2 p;
        p.x = bf16rne_pack(v.x, v.y);
        p.y = bf16rne_pack(v.z, v.w);
        const int ui = r * 32 + ((2 * c) ^ ((((unsigned)r >> 1) & 15) << 1));
        *reinterpret_cast<uint2*>(&k_lds[ui]) = p;   // ui even -> 8B aligned
    }
    // ---- stage this wave's q rows as packed bf16 ----
    {
        const int i = i0 + wave;
        const float* qp = qg + ((size_t)i * HKV_ + h) * (M_ * D_);
        const int off = lane * 4;                // float index within the row
        const f4 a = *reinterpret_cast<const f4*>(qp + off);
        const f4 b = *reinterpret_cast<const f4*>(qp + off + 256);
        uint2 pa, pb2;
        pa.x  = bf16rne_pack(a.x, a.y);
        pa.y  = bf16rne_pack(a.z, a.w);
        pb2.x = bf16rne_pack(b.x, b.y);
        pb2.y = bf16rne_pack(b.z, b.w);
        *reinterpret_cast<uint2*>(&q_lds[wave][off / 2])         = pa;
        *reinterpret_cast<uint2*>(&q_lds[wave][(off + 256) / 2]) = pb2;
    }
    __syncthreads();

    const int i   = i0 + wave;
    const int jlo = (i >= WIN_ - 1) ? (i - (WIN_ - 1)) : 0;
    const int cnt = i - jlo + 1;                 // 1..128 valid keys
    const int rlo = jlo - base;                  // rel idx of first valid key

    const int idx0 = 2 * lane;
    const int idx1 = idx0 + 1;
    const bool v0 = idx0 < cnt;
    const bool v1 = idx1 < cnt;
    int r0 = rlo + idx0; if (r0 > NKEY_ - 1) r0 = NKEY_ - 1;
    int r1 = rlo + idx1; if (r1 > NKEY_ - 1) r1 = NKEY_ - 1;

    float acc0[M_], acc1[M_];
    #pragma unroll
    for (int m = 0; m < M_; ++m) { acc0[m] = 0.f; acc1[m] = 0.f; }

    const unsigned* k0p = &k_lds[r0 * 32];
    const unsigned* k1p = &k_lds[r1 * 32];
    const int rot0 = (((unsigned)r0 >> 1) & 15) << 1;
    const int rot1 = (((unsigned)r1 >> 1) & 15) << 1;

    #pragma unroll
    for (int c = 0; c < 16; ++c) {
        const uint2 kw0 = *reinterpret_cast<const uint2*>(&k0p[(2 * c) ^ rot0]);
        const uint2 kw1 = *reinterpret_cast<const uint2*>(&k1p[(2 * c) ^ rot1]);
        const float k00 = __uint_as_float(kw0.x << 16);
        const float k01 = __uint_as_float(kw0.x & 0xFFFF0000u);
        const float k02 = __uint_as_float(kw0.y << 16);
        const float k03 = __uint_as_float(kw0.y & 0xFFFF0000u);
        const float k10 = __uint_as_float(kw1.x << 16);
        const float k11 = __uint_as_float(kw1.x & 0xFFFF0000u);
        const float k12 = __uint_as_float(kw1.y << 16);
        const float k13 = __uint_as_float(kw1.y & 0xFFFF0000u);
        #pragma unroll
        for (int m = 0; m < M_; ++m) {
            // wave-uniform broadcast read of 4 bf16-packed q values (8B)
            const uint2 qw = *reinterpret_cast<const uint2*>(
                &q_lds[wave][m * 32 + 2 * c]);
            const float q0 = __uint_as_float(qw.x << 16);
            const float q1 = __uint_as_float(qw.x & 0xFFFF0000u);
            const float q2 = __uint_as_float(qw.y << 16);
            const float q3 = __uint_as_float(qw.y & 0xFFFF0000u);
            acc0[m] = fmaf(q0, k00, acc0[m]);
            acc0[m] = fmaf(q1, k01, acc0[m]);
            acc0[m] = fmaf(q2, k02, acc0[m]);
            acc0[m] = fmaf(q3, k03, acc0[m]);
            acc1[m] = fmaf(q0, k10, acc1[m]);
            acc1[m] = fmaf(q1, k11, acc1[m]);
            acc1[m] = fmaf(q2, k12, acc1[m]);
            acc1[m] = fmaf(q3, k13, acc1[m]);
        }
    }

    // ---- per-m softmax (with sink) + full-row PLAIN contiguous store ----
    #pragma unroll
    for (int m = 0; m < M_; ++m) {
        float l0 = v0 ? acc0[m] * SCALE_ : -INFINITY;
        float l1 = v1 ? acc1[m] * SCALE_ : -INFINITY;
        float mx = fmaxf(l0, l1);
        #pragma unroll
        for (int s = 1; s < 64; s <<= 1)
            mx = fmaxf(mx, __shfl_xor(mx, s, 64));
        const float slog = sinks[h * M_ + m];
        mx = fmaxf(mx, slog);
        float p0 = __expf(l0 - mx);              // exp(-inf)=0 for masked keys
        float p1 = __expf(l1 - mx);
        float sum = p0 + p1;
        #pragma unroll
        for (int s = 1; s < 64; s <<= 1)
            sum += __shfl_xor(sum, s, 64);
        const float inv = 1.0f / (sum + __expf(slog - mx));
        p0 *= inv;
        p1 *= inv;

        float* pb = p_lds[wave][m & 1];          // double buffer
        pb[idx0 + (idx0 >> 4)] = p0;
        pb[idx1 + (idx1 >> 4)] = p1;
        asm volatile("s_waitcnt lgkmcnt(0)" ::: "memory");  // writes visible to wave

        // Full 4 KB row, 4 plain f4 stores per lane; each instruction covers
        // 1 KB contiguous = 8 full 128B lines sourced entirely from this wave.
        float* orow = outg + (((size_t)(h * M_ + m) * T_ + i) * T_);
        #pragma unroll
        for (int t = 0; t < 4; ++t) {
            const int j = t * 256 + lane * 4;    // float index in row
            f4 ov;
            #pragma unroll
            for (int u = 0; u < 4; ++u) {
                int idx = j + u - jlo;
                const bool in = (unsigned)idx < (unsigned)cnt;
                int ci = idx; if (ci < 0) ci = 0; if (ci > 127) ci = 127;
                const float val = pb[ci + (ci >> 4)];
                ov[u] = in ? val : 0.0f;
            }
            *reinterpret_cast<f4*>(orow + j) = ov;   // plain cached store
        }
    }
}

} // namespace

extern "C" void kernel_launch(void* const* d_in, const int* in_sizes, int n_in,
                              void* d_out, int out_size, void* d_ws, size_t ws_size,
                              hipStream_t stream) {
    const float* q     = (const float*)d_in[0];
    const float* k     = (const float*)d_in[1];
    const float* sinks = (const float*)d_in[2];
    float* out         = (float*)d_out;

    dim3 grid(HKV_ * (T_ / IB_));   // 8 heads * 128 i-blocks = 1024 blocks
    attn_qk_softmax<<<grid, NTHREADS_, 0, stream>>>(q, k, sinks, out);
}